// Round 7
// baseline (465.617 us; speedup 1.0000x reference)
//
#include <hip/hip_runtime.h>
#include <hip/hip_bf16.h>

#define LL 256
#define TT 128
#define CH 768
#define NB 16

typedef __attribute__((ext_vector_type(8))) short bf16x8;
typedef __attribute__((ext_vector_type(4))) float f32x4;

// ---------------- pack W_nuc transposed to bf16: Wp[(n*768+d)][c] = W[n][c][d] ----
__global__ __launch_bounds__(256) void pack_w_kernel(const float* __restrict__ W,
                                                     __hip_bfloat16* __restrict__ Wp) {
  __shared__ float s[64][65];
  int bid = blockIdx.x;
  int n = bid / 144, rem = bid % 144;
  int c0 = (rem / 12) * 64, d0 = (rem % 12) * 64;
  int t = threadIdx.x;
  int col = t & 63, rr = t >> 6;
  const float* Wn = W + (size_t)n * CH * CH;
#pragma unroll
  for (int it = 0; it < 16; ++it) {
    int r = it * 4 + rr;
    s[r][col] = Wn[(size_t)(c0 + r) * CH + d0 + col];
  }
  __syncthreads();
#pragma unroll
  for (int it = 0; it < 16; ++it) {
    int r = it * 4 + rr;  // d-offset
    Wp[(size_t)(n * CH + d0 + r) * CH + c0 + col] = __float2bfloat16(s[col][r]);
  }
}

// ---------------- token->nucleotide map into padded h buffer (bf16) ----------
// pad_h layout: [b][258][768], row r+1 = nucleotide row r; rows 0,257 zeroed.
__global__ __launch_bounds__(256) void tok_gather_kernel(const float* __restrict__ hidden,
                                                         const int* __restrict__ ptl,
                                                         __hip_bfloat16* __restrict__ pad_h) {
  int bid = blockIdx.x;  // b*256 + l
  int b = bid >> 8, l = bid & 255;
  __shared__ int vals[TT];
  __shared__ int tok_s;
  int t = threadIdx.x;
  if (t < TT) vals[t] = ptl[b * TT + t];
  __syncthreads();
  if (t == 0) {
    int run = 0, tk = 0;
    for (int q = 0; q < TT; ++q) { run += vals[q]; tk += (run <= l) ? 1 : 0; }
    tok_s = tk < TT ? tk : TT - 1;
  }
  __syncthreads();
  const float* src = hidden + ((size_t)b * TT + tok_s) * CH;
  __hip_bfloat16* dst = pad_h + ((size_t)b * 258 + l + 1) * CH;
#pragma unroll
  for (int q = 0; q < 3; ++q) dst[q * 256 + t] = __float2bfloat16(src[q * 256 + t]);
  // zero the pad rows (d_ws is poisoned before every launch)
  if (l == 0) {
    __hip_bfloat16* p0 = pad_h + (size_t)b * 258 * CH;
#pragma unroll
    for (int q = 0; q < 3; ++q) p0[q * 256 + t] = __float2bfloat16(0.f);
  }
  if (l == 255) {
    __hip_bfloat16* p1 = pad_h + ((size_t)b * 258 + 257) * CH;
#pragma unroll
    for (int q = 0; q < 3; ++q) p1[q * 256 + t] = __float2bfloat16(0.f);
  }
}

// ------- bf16 MFMA GEMM: C[M][N] = A[M][K] * B^T (B stored [N][K]) -----------
// MODE 0: plain fp32 store to C (ld = N).
// MODE 1: stem epilogue: col -> (o = col>>8, j = col&255); y0[o][row][j] =
//         relu(acc + bias[o]).  (A rows overlap: lda < K is allowed.)
template <int MODE>
__global__ __launch_bounds__(256) void gemm_bt_kernel(const __hip_bfloat16* __restrict__ A,
                                                      const __hip_bfloat16* __restrict__ B,
                                                      float* __restrict__ C,
                                                      int N, int K, int lda, int ldb,
                                                      long sA, long sB, long sC,
                                                      const float* __restrict__ bias,
                                                      float* __restrict__ y0out) {
  int z = blockIdx.z;
  A += (size_t)z * sA; B += (size_t)z * sB; C += (size_t)z * sC;
  int m0 = blockIdx.x * 128, n0 = blockIdx.y * 128;
  int t = threadIdx.x;
  int l = t & 63, w = t >> 6;
  int wm = w >> 1, wn = w & 1;
  __shared__ __align__(16) __hip_bfloat16 As[128 * 32];
  __shared__ __align__(16) __hip_bfloat16 Bs[128 * 32];
  f32x4 acc[4][4] = {};
  for (int k0 = 0; k0 < K; k0 += 32) {
    __syncthreads();
#pragma unroll
    for (int q = 0; q < 2; ++q) {
      int idx = q * 256 + t;
      int row = idx >> 2, k8 = (idx & 3) * 8;
      *(int4*)&As[idx * 8] = *(const int4*)(A + (size_t)(m0 + row) * lda + k0 + k8);
      *(int4*)&Bs[idx * 8] = *(const int4*)(B + (size_t)(n0 + row) * ldb + k0 + k8);
    }
    __syncthreads();
    bf16x8 a[4], b[4];
    int kb = (l >> 4) * 8;
    int rA = wm * 64 + (l & 15);
    int rB = wn * 64 + (l & 15);
#pragma unroll
    for (int m = 0; m < 4; ++m) a[m] = *(const bf16x8*)&As[(rA + m * 16) * 32 + kb];
#pragma unroll
    for (int n = 0; n < 4; ++n) b[n] = *(const bf16x8*)&Bs[(rB + n * 16) * 32 + kb];
#pragma unroll
    for (int m = 0; m < 4; ++m)
#pragma unroll
      for (int n = 0; n < 4; ++n)
        acc[m][n] = __builtin_amdgcn_mfma_f32_16x16x32_bf16(a[m], b[n], acc[m][n], 0, 0, 0);
  }
  int row0 = m0 + wm * 64 + ((l >> 4) << 2);
  int col0 = n0 + wn * 64 + (l & 15);
#pragma unroll
  for (int m = 0; m < 4; ++m)
#pragma unroll
    for (int n = 0; n < 4; ++n) {
      if (MODE == 0) {
#pragma unroll
        for (int r = 0; r < 4; ++r)
          C[(size_t)(row0 + m * 16 + r) * N + col0 + n * 16] = acc[m][n][r];
      } else {
        int colg = col0 + n * 16;
        int o = colg >> 8, j = colg & 255;
        float bo = bias[o];
#pragma unroll
        for (int r = 0; r < 4; ++r) {
          int row = row0 + m * 16 + r;
          y0out[(size_t)o * 65536 + row * 256 + j] = fmaxf(acc[m][n][r] + bo, 0.f);
        }
      }
    }
}

// ---------------- per-row select of the 5-way MLP + bias + mask --------------
// writes h (bf16) back into pad_h interior.
__global__ __launch_bounds__(256) void select_kernel(const float* __restrict__ G5,
                                                     const float* __restrict__ b_nuc,
                                                     const float* __restrict__ wmask,
                                                     const int* __restrict__ nuc_ids,
                                                     __hip_bfloat16* __restrict__ pad_h) {
  int row = blockIdx.x;  // 0..511
  int b = row >> 8, l = row & 255;
  int t = threadIdx.x;
  int n = nuc_ids[row];
  n = n < 0 ? 0 : (n > 4 ? 4 : n);
  float wm = wmask[row];
  const float* g = G5 + (size_t)row * 3840 + (size_t)n * CH;
  const float* bn = b_nuc + (size_t)n * CH;
  __hip_bfloat16* dst = pad_h + ((size_t)b * 258 + l + 1) * CH;
#pragma unroll
  for (int q = 0; q < 3; ++q) {
    int d = q * 256 + t;
    dst[d] = __float2bfloat16((g[d] + bn[d]) * wm);
  }
}

// ------- cB[(o*256+j)][di*768+k] = sum_dj w_in[o,k,di,dj]*h[j+dj-1,k] --------
__global__ __launch_bounds__(256) void c_kernel(const __hip_bfloat16* __restrict__ ph,
                                                const float* __restrict__ w_in,
                                                __hip_bfloat16* __restrict__ cB) {
  int jt = blockIdx.x;  // 0..7
  int od = blockIdx.y;  // 0..47  (o*3+di)
  int o = od / 3, di = od % 3;
  int t = threadIdx.x;
  __shared__ float wk[3][CH];
  for (int idx = t; idx < 3 * CH; idx += 256) {
    int k = idx / 3, dj = idx % 3;
    wk[dj][k] = w_in[((size_t)(o * CH + k) * 3 + di) * 3 + dj];
  }
  __syncthreads();
  int j0 = jt * 32;
  for (int j = j0; j < j0 + 32; ++j) {
    __hip_bfloat16* dst = cB + ((size_t)(o * 256 + j) * 3 + di) * CH;
#pragma unroll
    for (int q = 0; q < 3; ++q) {
      int k = q * 256 + t;
      float acc = 0.f;
#pragma unroll
      for (int dj = 0; dj < 3; ++dj)  // pad row (j+dj-1)+1 = j+dj, always valid
        acc += wk[dj][k] * __bfloat162float(ph[(size_t)(j + dj) * CH + k]);
      dst[k] = __float2bfloat16(acc);
    }
  }
}

// ---------------- direct 16->16 3x3 conv (fp32), optional residual+relu -------
__global__ __launch_bounds__(256) void conv16_kernel(const float* __restrict__ in,
                                                     const float* __restrict__ w,
                                                     const float* __restrict__ bias,
                                                     const float* __restrict__ res,
                                                     float* __restrict__ out,
                                                     int relu) {
  int bid = blockIdx.x;
  int tj = bid & 7;
  int ti = (bid >> 3) & 15;
  int b = bid >> 7;
  int i0 = ti * 16, j0 = tj * 32;
  int t = threadIdx.x;
  __shared__ float wsm[NB * NB * 9];
  __shared__ float in_s[18][36];
  for (int idx = t; idx < NB * NB * 9; idx += 256) wsm[idx] = w[idx];
  int o = t >> 4;
  int s = t & 15;
  int si = (s >> 2) * 4;
  int sj = (s & 3) * 8;
  float acc[4][8];
#pragma unroll
  for (int ii = 0; ii < 4; ++ii)
#pragma unroll
    for (int jj = 0; jj < 8; ++jj) acc[ii][jj] = 0.f;

  for (int k = 0; k < NB; ++k) {
    __syncthreads();
    for (int idx = t; idx < 18 * 34; idx += 256) {
      int r = idx / 34, c = idx % 34;
      int gi = i0 - 1 + r, gj = j0 - 1 + c;
      float v = 0.f;
      if (gi >= 0 && gi < LL && gj >= 0 && gj < LL)
        v = in[((size_t)(b * NB + k) * LL + gi) * LL + gj];
      in_s[r][c] = v;
    }
    __syncthreads();
    float f[6][12];
#pragma unroll
    for (int r = 0; r < 6; ++r)
#pragma unroll
      for (int cq = 0; cq < 3; ++cq)
        *(float4*)&f[r][cq * 4] = *(const float4*)&in_s[si + r][sj + cq * 4];
    float w9[9];
#pragma unroll
    for (int d = 0; d < 9; ++d) w9[d] = wsm[(o * NB + k) * 9 + d];
#pragma unroll
    for (int ii = 0; ii < 4; ++ii)
#pragma unroll
      for (int jj = 0; jj < 8; ++jj)
#pragma unroll
        for (int di = 0; di < 3; ++di)
#pragma unroll
          for (int dj = 0; dj < 3; ++dj)
            acc[ii][jj] += w9[di * 3 + dj] * f[ii + di][jj + dj];
  }
  float bo = bias[o];
#pragma unroll
  for (int ii = 0; ii < 4; ++ii)
#pragma unroll
    for (int jj = 0; jj < 8; ++jj) {
      int gi = i0 + si + ii, gj = j0 + sj + jj;
      size_t oidx = ((size_t)(b * NB + o) * LL + gi) * LL + gj;
      float v = acc[ii][jj] + bo;
      if (res) v += res[oidx];
      if (relu) v = fmaxf(v, 0.f);
      out[oidx] = v;
    }
}

// ---------------- 1x1 head, fp32 output --------------------------------------
__global__ __launch_bounds__(256) void head_kernel(const float* __restrict__ y,
                                                   const float* __restrict__ w_out,
                                                   const float* __restrict__ b_out,
                                                   float* __restrict__ out) {
  int bi = blockIdx.x;  // b*256 + i
  int b = bi >> 8, i = bi & 255;
  int j = threadIdx.x;
  float s = b_out[0];
#pragma unroll
  for (int o = 0; o < NB; ++o)
    s += w_out[o] * y[(((size_t)b * NB + o) * LL + i) * LL + j];
  out[(size_t)bi * LL + j] = s;
}

extern "C" void kernel_launch(void* const* d_in, const int* in_sizes, int n_in,
                              void* d_out, int out_size, void* d_ws, size_t ws_size,
                              hipStream_t stream) {
  const float* hidden = (const float*)d_in[0];
  const float* wmask = (const float*)d_in[1];
  const float* W_nuc = (const float*)d_in[2];
  const float* b_nuc = (const float*)d_in[3];
  const float* w_in = (const float*)d_in[4];
  const float* b_in = (const float*)d_in[5];
  const float* w1a = (const float*)d_in[6];
  const float* b1a = (const float*)d_in[7];
  const float* w1b = (const float*)d_in[8];
  const float* b1b = (const float*)d_in[9];
  const float* w2a = (const float*)d_in[10];
  const float* b2a = (const float*)d_in[11];
  const float* w2b = (const float*)d_in[12];
  const float* b2b = (const float*)d_in[13];
  const float* w_out = (const float*)d_in[14];
  const float* b_out = (const float*)d_in[15];
  const int* ptl = (const int*)d_in[16];
  const int* nuc_ids = (const int*)d_in[17];
  float* out = (float*)d_out;  // reference output dtype is float32

  // workspace layout (peak 26.8 MB)
  char* ws = (char*)d_ws;
  __hip_bfloat16* pad_h = (__hip_bfloat16*)(ws);              // 2*258*768*2 = 792,576
  __hip_bfloat16* Wp = (__hip_bfloat16*)(ws + 792576);        // 3840*768*2  = 5,898,240
  float* G5 = (float*)(ws + 6690816);                         // 512*3840*4  = 7,864,320 (ends 14,555,136)
  __hip_bfloat16* cB = (__hip_bfloat16*)(ws + 792576);        // 4096*2304*2 = 18,874,368 (aliases Wp+G5; ends 19,666,944)
  float* y0 = (float*)(ws + 19666944);                        // 2*16*256*256*4 = 8,388,608 (ends 28,055,552)
  float* ta = (float*)(ws + 792576);                          // 8,388,608 (aliases dead cB)
  float* tb = (float*)(ws + 9181184);                         // 8,388,608 (ends 17,569,792)

  const long PHB = 258 * CH;  // per-batch pad_h stride (elements)

  pack_w_kernel<<<720, 256, 0, stream>>>(W_nuc, Wp);
  tok_gather_kernel<<<512, 256, 0, stream>>>(hidden, ptl, pad_h);
  // G5[b*256+l][n*768+d] = map @ Wp^T   (M=256 per batch, N=3840, K=768)
  gemm_bt_kernel<0><<<dim3(2, 30, 2), 256, 0, stream>>>(
      pad_h + CH, Wp, G5, 3840, CH, CH, CH, PHB, 0, (long)256 * 3840, nullptr, nullptr);
  select_kernel<<<512, 256, 0, stream>>>(G5, b_nuc, wmask, nuc_ids, pad_h);
  // stem per batch: c-precompute then fused GEMM (M=256, N=4096, K=2304, lda=768)
  for (int b = 0; b < 2; ++b) {
    c_kernel<<<dim3(8, 48), 256, 0, stream>>>(pad_h + (size_t)b * PHB, w_in, cB);
    gemm_bt_kernel<1><<<dim3(2, 32), 256, 0, stream>>>(
        pad_h + (size_t)b * PHB, cB, nullptr, 4096, 2304, CH, 2304, 0, 0, 0,
        b_in, y0 + (size_t)b * NB * 65536);
  }
  conv16_kernel<<<256, 256, 0, stream>>>(y0, w1a, b1a, nullptr, ta, 1);
  conv16_kernel<<<256, 256, 0, stream>>>(ta, w1b, b1b, y0, tb, 1);
  conv16_kernel<<<256, 256, 0, stream>>>(tb, w2a, b2a, nullptr, ta, 1);
  conv16_kernel<<<256, 256, 0, stream>>>(ta, w2b, b2b, tb, y0, 1);
  head_kernel<<<512, 256, 0, stream>>>(y0, w_out, b_out, out);
}

// Round 9
// 250.974 us; speedup vs baseline: 1.8552x; 1.8552x over previous
//
#include <hip/hip_runtime.h>
#include <hip/hip_bf16.h>

#define LL 256
#define TT 128
#define CH 768
#define NB 16

typedef __attribute__((ext_vector_type(8))) short bf16x8;
typedef __attribute__((ext_vector_type(4))) float f32x4;

// ---------------- pack W_nuc transposed to bf16: Wp[(n*768+d)][c] = W[n][c][d] ----
__global__ __launch_bounds__(256) void pack_w_kernel(const float* __restrict__ W,
                                                     __hip_bfloat16* __restrict__ Wp) {
  __shared__ float s[64][65];
  int bid = blockIdx.x;
  int n = bid / 144, rem = bid % 144;
  int c0 = (rem / 12) * 64, d0 = (rem % 12) * 64;
  int t = threadIdx.x;
  int col = t & 63, rr = t >> 6;
  const float* Wn = W + (size_t)n * CH * CH;
#pragma unroll
  for (int it = 0; it < 16; ++it) {
    int r = it * 4 + rr;
    s[r][col] = Wn[(size_t)(c0 + r) * CH + d0 + col];
  }
  __syncthreads();
#pragma unroll
  for (int it = 0; it < 16; ++it) {
    int r = it * 4 + rr;  // d-offset
    Wp[(size_t)(n * CH + d0 + r) * CH + c0 + col] = __float2bfloat16(s[col][r]);
  }
}

// ---------------- pack conv weights: wq[c][o][kq], kq = dd*16+ch, 160 padded ----
__global__ __launch_bounds__(256) void pack_wq_kernel(const float* __restrict__ wa,
                                                      const float* __restrict__ wb,
                                                      const float* __restrict__ wc,
                                                      const float* __restrict__ wd,
                                                      __hip_bfloat16* __restrict__ wq) {
  const float* srcs[4] = {wa, wb, wc, wd};
  int c = blockIdx.x;
  const float* src = srcs[c];
  int t = threadIdx.x;
  for (int idx = t; idx < 2560; idx += 256) {
    int o = idx / 160, kq = idx % 160;
    int dd = kq >> 4, ch = kq & 15;
    float v = (dd < 9) ? src[(o * 16 + ch) * 9 + dd] : 0.f;  // w[o][ch][di][dj]
    wq[c * 2560 + idx] = __float2bfloat16(v);
  }
}

// ---------------- token->nucleotide map into padded h buffer (bf16) ----------
// pad_h layout: [b][258][768], row r+1 = nucleotide row r; rows 0,257 zeroed.
__global__ __launch_bounds__(256) void tok_gather_kernel(const float* __restrict__ hidden,
                                                         const int* __restrict__ ptl,
                                                         __hip_bfloat16* __restrict__ pad_h) {
  int bid = blockIdx.x;  // b*256 + l
  int b = bid >> 8, l = bid & 255;
  __shared__ int vals[TT];
  __shared__ int tok_s;
  int t = threadIdx.x;
  if (t < TT) vals[t] = ptl[b * TT + t];
  __syncthreads();
  if (t == 0) {
    int run = 0, tk = 0;
    for (int q = 0; q < TT; ++q) { run += vals[q]; tk += (run <= l) ? 1 : 0; }
    tok_s = tk < TT ? tk : TT - 1;
  }
  __syncthreads();
  const float* src = hidden + ((size_t)b * TT + tok_s) * CH;
  __hip_bfloat16* dst = pad_h + ((size_t)b * 258 + l + 1) * CH;
#pragma unroll
  for (int q = 0; q < 3; ++q) dst[q * 256 + t] = __float2bfloat16(src[q * 256 + t]);
  if (l == 0) {
    __hip_bfloat16* p0 = pad_h + (size_t)b * 258 * CH;
#pragma unroll
    for (int q = 0; q < 3; ++q) p0[q * 256 + t] = __float2bfloat16(0.f);
  }
  if (l == 255) {
    __hip_bfloat16* p1 = pad_h + ((size_t)b * 258 + 257) * CH;
#pragma unroll
    for (int q = 0; q < 3; ++q) p1[q * 256 + t] = __float2bfloat16(0.f);
  }
}

// ------- 64x64-tile bf16 MFMA GEMM, reg-dbuf LDS, C = A * B^T ----------------
// MODE 0: fp32 store to C (ld = N).
// MODE 1: stem epilogue -> channels-last padded bf16: col=(o<<8)|j;
//         outbf[((row+1)*258 + (j+1))*16 + o] = bf16(relu(acc+bias[o])).
template <int MODE>
__global__ __launch_bounds__(256) void gemm64_kernel(const __hip_bfloat16* __restrict__ A,
                                                     const __hip_bfloat16* __restrict__ B,
                                                     float* __restrict__ C,
                                                     int N, int K, int lda, int ldb,
                                                     long sA, long sB, long sC,
                                                     const float* __restrict__ bias,
                                                     __hip_bfloat16* __restrict__ outbf) {
  int z = blockIdx.z;
  A += (size_t)z * sA; B += (size_t)z * sB;
  if (MODE == 0) C += (size_t)z * sC;
  int m0 = blockIdx.x * 64, n0 = blockIdx.y * 64;
  int t = threadIdx.x, l = t & 63, w = t >> 6, wm = w >> 1, wn = w & 1;
  __shared__ __align__(16) __hip_bfloat16 As[2][64 * 32];
  __shared__ __align__(16) __hip_bfloat16 Bs[2][64 * 32];
  int row = t >> 2, k8 = (t & 3) * 8;
  const __hip_bfloat16* pa = A + (size_t)(m0 + row) * lda + k8;
  const __hip_bfloat16* pb = B + (size_t)(n0 + row) * ldb + k8;
  bf16x8 ra = *(const bf16x8*)pa;
  bf16x8 rb = *(const bf16x8*)pb;
  f32x4 acc[2][2] = {};
  int kb = (l >> 4) * 8, rA = wm * 32 + (l & 15), rB = wn * 32 + (l & 15);
  int p = 0;
  for (int k0 = 0; k0 < K; k0 += 32) {
    *(bf16x8*)&As[p][t * 8] = ra;
    *(bf16x8*)&Bs[p][t * 8] = rb;
    __syncthreads();
    if (k0 + 32 < K) {  // prefetch next tile into regs; latency hides under MFMA
      ra = *(const bf16x8*)(pa + k0 + 32);
      rb = *(const bf16x8*)(pb + k0 + 32);
    }
    bf16x8 a0 = *(const bf16x8*)&As[p][rA * 32 + kb];
    bf16x8 a1 = *(const bf16x8*)&As[p][(rA + 16) * 32 + kb];
    bf16x8 b0 = *(const bf16x8*)&Bs[p][rB * 32 + kb];
    bf16x8 b1 = *(const bf16x8*)&Bs[p][(rB + 16) * 32 + kb];
    acc[0][0] = __builtin_amdgcn_mfma_f32_16x16x32_bf16(a0, b0, acc[0][0], 0, 0, 0);
    acc[0][1] = __builtin_amdgcn_mfma_f32_16x16x32_bf16(a0, b1, acc[0][1], 0, 0, 0);
    acc[1][0] = __builtin_amdgcn_mfma_f32_16x16x32_bf16(a1, b0, acc[1][0], 0, 0, 0);
    acc[1][1] = __builtin_amdgcn_mfma_f32_16x16x32_bf16(a1, b1, acc[1][1], 0, 0, 0);
    p ^= 1;
  }
  int row0 = m0 + wm * 32 + ((l >> 4) << 2);
  int col0 = n0 + wn * 32 + (l & 15);
#pragma unroll
  for (int m = 0; m < 2; ++m)
#pragma unroll
    for (int n = 0; n < 2; ++n) {
      if (MODE == 0) {
#pragma unroll
        for (int r = 0; r < 4; ++r)
          C[(size_t)(row0 + m * 16 + r) * N + col0 + n * 16] = acc[m][n][r];
      } else {
        int colg = col0 + n * 16;
        int o = colg >> 8, j = colg & 255;
        float bo = bias[o];
#pragma unroll
        for (int r = 0; r < 4; ++r) {
          int i = row0 + m * 16 + r;
          outbf[(((size_t)i + 1) * 258 + (j + 1)) * 16 + o] =
              __float2bfloat16(fmaxf(acc[m][n][r] + bo, 0.f));
        }
      }
    }
}

// ---------------- per-row select of the 5-way MLP + bias + mask --------------
__global__ __launch_bounds__(256) void select_kernel(const float* __restrict__ G5,
                                                     const float* __restrict__ b_nuc,
                                                     const float* __restrict__ wmask,
                                                     const int* __restrict__ nuc_ids,
                                                     __hip_bfloat16* __restrict__ pad_h) {
  int row = blockIdx.x;  // 0..511
  int b = row >> 8, l = row & 255;
  int t = threadIdx.x;
  int n = nuc_ids[row];
  n = n < 0 ? 0 : (n > 4 ? 4 : n);
  float wm = wmask[row];
  const float* g = G5 + (size_t)row * 3840 + (size_t)n * CH;
  const float* bn = b_nuc + (size_t)n * CH;
  __hip_bfloat16* dst = pad_h + ((size_t)b * 258 + l + 1) * CH;
#pragma unroll
  for (int q = 0; q < 3; ++q) {
    int d = q * 256 + t;
    dst[d] = __float2bfloat16((g[d] + bn[d]) * wm);
  }
}

// ------- cB[(o*256+j)][di*768+k] = sum_dj w_in[o,k,di,dj]*h[j+dj-1,k] --------
__global__ __launch_bounds__(256) void c_kernel(const __hip_bfloat16* __restrict__ ph,
                                                const float* __restrict__ w_in,
                                                __hip_bfloat16* __restrict__ cB) {
  int jt = blockIdx.x;  // 0..7
  int od = blockIdx.y;  // 0..47  (o*3+di)
  int o = od / 3, di = od % 3;
  int t = threadIdx.x;
  __shared__ float wk[3][CH];
  for (int idx = t; idx < 3 * CH; idx += 256) {
    int k = idx / 3, dj = idx % 3;
    wk[dj][k] = w_in[((size_t)(o * CH + k) * 3 + di) * 3 + dj];
  }
  __syncthreads();
  int j0 = jt * 32;
  for (int j = j0; j < j0 + 32; ++j) {
    __hip_bfloat16* dst = cB + ((size_t)(o * 256 + j) * 3 + di) * CH;
#pragma unroll
    for (int q = 0; q < 3; ++q) {
      int k = q * 256 + t;
      float acc = 0.f;
#pragma unroll
      for (int dj = 0; dj < 3; ++dj)  // pad row (j+dj-1)+1 = j+dj, always valid
        acc += wk[dj][k] * __bfloat162float(ph[(size_t)(j + dj) * CH + k]);
      dst[k] = __float2bfloat16(acc);
    }
  }
}

// ------- 16->16 3x3 conv, channels-last padded bf16, MFMA implicit GEMM ------
// act layout: [b][258][258][16] bf16, pad ring zero. out = relu(conv+bias[+res])
__global__ __launch_bounds__(256) void conv_mfma_kernel(const __hip_bfloat16* __restrict__ in,
                                                        const __hip_bfloat16* __restrict__ wq,
                                                        const float* __restrict__ bias,
                                                        const __hip_bfloat16* __restrict__ res,
                                                        __hip_bfloat16* __restrict__ outp) {
  __shared__ __hip_bfloat16 wl[16 * 160];
  int t = threadIdx.x;
  for (int idx = t; idx < 320; idx += 256)
    ((bf16x8*)wl)[idx] = ((const bf16x8*)wq)[idx];
  __syncthreads();
  int l = t & 63, w = t >> 6;
  int part = l >> 4, lane16 = l & 15;
  int hi = part >> 1, ch0 = (part & 1) * 8;
  int offs[5];
  bf16x8 wf[5];
#pragma unroll
  for (int kk = 0; kk < 5; ++kk) {
    int dd = 2 * kk + hi;
    if (dd > 8) dd = 0;  // k>=144 has zero weights; read a valid addr
    offs[kk] = ((dd / 3) * 258 + (dd % 3)) * 16;
    wf[kk] = *(const bf16x8*)&wl[lane16 * 160 + kk * 32 + part * 8];
  }
  float bo = bias[lane16];
#pragma unroll
  for (int it = 0; it < 4; ++it) {
    int g = (blockIdx.x * 4 + w) * 4 + it;  // 0..8191 pixel-groups
    int b = g >> 12, idx = g & 4095;
    int i = idx >> 4, j0 = (idx & 15) << 4;
    size_t base = (((size_t)b * 258 + i) * 258 + (j0 + lane16)) * 16 + ch0;
    f32x4 acc = {};
#pragma unroll
    for (int kk = 0; kk < 5; ++kk) {
      bf16x8 af = *(const bf16x8*)&in[base + offs[kk]];
      acc = __builtin_amdgcn_mfma_f32_16x16x32_bf16(af, wf[kk], acc, 0, 0, 0);
    }
    // D: col=lane16=o, row=part*4+r = pixel within group
    size_t obase = (((size_t)b * 258 + i + 1) * 258 + (j0 + part * 4 + 1)) * 16 + lane16;
#pragma unroll
    for (int r = 0; r < 4; ++r) {
      float v = acc[r] + bo;
      if (res) v += __bfloat162float(res[obase + (size_t)r * 16]);
      outp[obase + (size_t)r * 16] = __float2bfloat16(fmaxf(v, 0.f));
    }
  }
}

// ---------------- 1x1 head from channels-last bf16, fp32 output --------------
__global__ __launch_bounds__(256) void head_kernel(const __hip_bfloat16* __restrict__ y,
                                                   const float* __restrict__ w_out,
                                                   const float* __restrict__ b_out,
                                                   float* __restrict__ out) {
  __shared__ float wsm[16];
  int t = threadIdx.x;
  if (t < 16) wsm[t] = w_out[t];
  __syncthreads();
  int bi = blockIdx.x;  // b*256 + i
  int b = bi >> 8, i = bi & 255;
  const __hip_bfloat16* p = y + (((size_t)b * 258 + i + 1) * 258 + (t + 1)) * 16;
  float s = b_out[0];
#pragma unroll
  for (int o = 0; o < 16; ++o) s += wsm[o] * __bfloat162float(p[o]);
  out[(size_t)bi * 256 + t] = s;
}

extern "C" void kernel_launch(void* const* d_in, const int* in_sizes, int n_in,
                              void* d_out, int out_size, void* d_ws, size_t ws_size,
                              hipStream_t stream) {
  const float* hidden = (const float*)d_in[0];
  const float* wmask = (const float*)d_in[1];
  const float* W_nuc = (const float*)d_in[2];
  const float* b_nuc = (const float*)d_in[3];
  const float* w_in = (const float*)d_in[4];
  const float* b_in = (const float*)d_in[5];
  const float* w1a = (const float*)d_in[6];
  const float* b1a = (const float*)d_in[7];
  const float* w1b = (const float*)d_in[8];
  const float* b1b = (const float*)d_in[9];
  const float* w2a = (const float*)d_in[10];
  const float* b2a = (const float*)d_in[11];
  const float* w2b = (const float*)d_in[12];
  const float* b2b = (const float*)d_in[13];
  const float* w_out = (const float*)d_in[14];
  const float* b_out = (const float*)d_in[15];
  const int* ptl = (const int*)d_in[16];
  const int* nuc_ids = (const int*)d_in[17];
  float* out = (float*)d_out;

  // workspace layout (peak 23.95 MB; 28.06 MB proven available in round 7)
  char* ws = (char*)d_ws;
  __hip_bfloat16* pad_h = (__hip_bfloat16*)(ws);                // 792,576
  __hip_bfloat16* Wp = (__hip_bfloat16*)(ws + 792576);          // 5,898,240 (ends 6,690,816)
  float* G5 = (float*)(ws + 6690816);                           // 7,864,320 (ends 14,555,136)
  __hip_bfloat16* cB = (__hip_bfloat16*)(ws + 792576);          // 18,874,368 aliases Wp+G5 (ends 19,666,944)
  __hip_bfloat16* act1 = (__hip_bfloat16*)(ws + 792576);        // 4,259,328 aliases dead cB
  __hip_bfloat16* act2 = (__hip_bfloat16*)(ws + 5051904);       // 4,259,328 (ends 9,311,232)
  __hip_bfloat16* act0 = (__hip_bfloat16*)(ws + 19666944);      // 4,259,328 (ends 23,926,272)
  __hip_bfloat16* wq = (__hip_bfloat16*)(ws + 23926272);        // 20,480 (ends 23,946,752)

  const long PHB = 258 * CH;        // per-batch pad_h stride (elements)
  const long ACT = 258 * 258 * 16;  // per-batch act stride (elements)

  pack_w_kernel<<<720, 256, 0, stream>>>(W_nuc, Wp);
  pack_wq_kernel<<<4, 256, 0, stream>>>(w1a, w1b, w2a, w2b, wq);
  hipMemsetAsync(act0, 0, 4259328, stream);  // zero pad ring (interior overwritten by stem)
  tok_gather_kernel<<<512, 256, 0, stream>>>(hidden, ptl, pad_h);
  // phase-A: G5[b*256+l][n*768+d] = map @ Wp^T   (M=256/batch, N=3840, K=768)
  gemm64_kernel<0><<<dim3(4, 60, 2), 256, 0, stream>>>(
      pad_h + CH, Wp, G5, 3840, CH, CH, CH, PHB, 0, (long)256 * 3840, nullptr, nullptr);
  select_kernel<<<512, 256, 0, stream>>>(G5, b_nuc, wmask, nuc_ids, pad_h);
  // stem per batch: c-precompute, then fused GEMM (M=256, N=4096, K=2304, lda=768)
  for (int b = 0; b < 2; ++b) {
    c_kernel<<<dim3(8, 48), 256, 0, stream>>>(pad_h + (size_t)b * PHB, w_in, cB);
    gemm64_kernel<1><<<dim3(4, 64), 256, 0, stream>>>(
        pad_h + (size_t)b * PHB, cB, nullptr, 4096, 2304, CH, 2304, 0, 0, 0,
        b_in, act0 + (size_t)b * ACT);
  }
  hipMemsetAsync(act1, 0, 8518656, stream);  // act1+act2 contiguous; after cB is dead
  conv_mfma_kernel<<<512, 256, 0, stream>>>(act0, wq, b1a, nullptr, act1);
  conv_mfma_kernel<<<512, 256, 0, stream>>>(act1, wq + 2560, b1b, act0, act2);
  conv_mfma_kernel<<<512, 256, 0, stream>>>(act2, wq + 5120, b2a, nullptr, act1);
  conv_mfma_kernel<<<512, 256, 0, stream>>>(act1, wq + 7680, b2b, act2, act0);
  head_kernel<<<512, 256, 0, stream>>>(act0, w_out, b_out, out);
}

// Round 12
// 194.431 us; speedup vs baseline: 2.3948x; 1.2908x over previous
//
#include <hip/hip_runtime.h>
#include <hip/hip_bf16.h>

#define LL 256
#define TT 128
#define CH 768
#define NB 16

typedef __attribute__((ext_vector_type(8))) short bf16x8;
typedef __attribute__((ext_vector_type(4))) float f32x4;

__device__ __forceinline__ float b2f(short s) {
  union { unsigned u; float f; } x;
  x.u = ((unsigned)(unsigned short)s) << 16;
  return x.f;
}
__device__ __forceinline__ short f2b(float v) {
  __hip_bfloat16 hb = __float2bfloat16(v);
  return *reinterpret_cast<short*>(&hb);
}

// ---------------- pack W_nuc transposed to bf16: Wp[(n*768+d)][c] = W[n][c][d] ----
__global__ __launch_bounds__(256) void pack_w_kernel(const float* __restrict__ W,
                                                     __hip_bfloat16* __restrict__ Wp) {
  __shared__ float s[64][65];
  int bid = blockIdx.x;
  int n = bid / 144, rem = bid % 144;
  int c0 = (rem / 12) * 64, d0 = (rem % 12) * 64;
  int t = threadIdx.x;
  int col = t & 63, rr = t >> 6;
  const float* Wn = W + (size_t)n * CH * CH;
#pragma unroll
  for (int it = 0; it < 16; ++it) {
    int r = it * 4 + rr;
    s[r][col] = Wn[(size_t)(c0 + r) * CH + d0 + col];
  }
  __syncthreads();
#pragma unroll
  for (int it = 0; it < 16; ++it) {
    int r = it * 4 + rr;  // d-offset
    Wp[(size_t)(n * CH + d0 + r) * CH + c0 + col] = __float2bfloat16(s[col][r]);
  }
}

// ---------------- pack conv weights: wq[c][o][kq], kq = dd*16+ch, 160 padded ----
__global__ __launch_bounds__(256) void pack_wq_kernel(const float* __restrict__ wa,
                                                      const float* __restrict__ wb,
                                                      const float* __restrict__ wc,
                                                      const float* __restrict__ wd,
                                                      __hip_bfloat16* __restrict__ wq) {
  const float* srcs[4] = {wa, wb, wc, wd};
  int c = blockIdx.x;
  const float* src = srcs[c];
  int t = threadIdx.x;
  for (int idx = t; idx < 2560; idx += 256) {
    int o = idx / 160, kq = idx % 160;
    int dd = kq >> 4, ch = kq & 15;
    float v = (dd < 9) ? src[(o * 16 + ch) * 9 + dd] : 0.f;  // w[o][ch][di][dj]
    wq[c * 2560 + idx] = __float2bfloat16(v);
  }
}

// ---------------- token->nucleotide map into padded h buffer (bf16) ----------
// pad_h layout: [b][258][768], row r+1 = nucleotide row r; rows 0,257 zeroed.
__global__ __launch_bounds__(256) void tok_gather_kernel(const float* __restrict__ hidden,
                                                         const int* __restrict__ ptl,
                                                         __hip_bfloat16* __restrict__ pad_h) {
  int bid = blockIdx.x;  // b*256 + l
  int b = bid >> 8, l = bid & 255;
  __shared__ int vals[TT];
  __shared__ int tok_s;
  int t = threadIdx.x;
  if (t < TT) vals[t] = ptl[b * TT + t];
  __syncthreads();
  if (t == 0) {
    int run = 0, tk = 0;
    for (int q = 0; q < TT; ++q) { run += vals[q]; tk += (run <= l) ? 1 : 0; }
    tok_s = tk < TT ? tk : TT - 1;
  }
  __syncthreads();
  const float* src = hidden + ((size_t)b * TT + tok_s) * CH;
  __hip_bfloat16* dst = pad_h + ((size_t)b * 258 + l + 1) * CH;
#pragma unroll
  for (int q = 0; q < 3; ++q) dst[q * 256 + t] = __float2bfloat16(src[q * 256 + t]);
  if (l == 0) {
    __hip_bfloat16* p0 = pad_h + (size_t)b * 258 * CH;
#pragma unroll
    for (int q = 0; q < 3; ++q) p0[q * 256 + t] = __float2bfloat16(0.f);
  }
  if (l == 255) {
    __hip_bfloat16* p1 = pad_h + ((size_t)b * 258 + 257) * CH;
#pragma unroll
    for (int q = 0; q < 3; ++q) p1[q * 256 + t] = __float2bfloat16(0.f);
  }
}

// ------- 64x64-tile bf16 MFMA GEMM, K-step 64, reg-dbuf LDS, XOR-swizzled ----
// C = A * B^T (B stored [N][K]).
// MODE 0: fp32 store to C (ld = N), 3-D grid (mx, ny, z).
// MODE 1: 1-D grid of 512, XCD-swizzled: bid -> (mx=(bid>>3)&3, pair=(bid>>5)*8
//         +(bid&7), ny=pair>>1, z=pair&1). Stem epilogue: col=(o<<8)|j ->
//         outbf[z*sC + ((row+1)*258+(j+1))*16+o] = bf16(relu(acc+bias[o])).
template <int MODE>
__global__ __launch_bounds__(256) void gemm64_kernel(const __hip_bfloat16* __restrict__ A,
                                                     const __hip_bfloat16* __restrict__ B,
                                                     float* __restrict__ C,
                                                     int N, int K, int lda, int ldb,
                                                     long sA, long sB, long sC,
                                                     const float* __restrict__ bias,
                                                     __hip_bfloat16* __restrict__ outbf) {
  int mx, ny, zz;
  if (MODE == 1) {
    int bid = blockIdx.x;
    mx = (bid >> 3) & 3;
    int pair = (bid >> 5) * 8 + (bid & 7);
    ny = pair >> 1;
    zz = pair & 1;
  } else {
    mx = blockIdx.x; ny = blockIdx.y; zz = blockIdx.z;
  }
  A += (size_t)zz * sA;
  B += (size_t)zz * sB;
  if (MODE == 0) C += (size_t)zz * sC;
  int m0 = mx * 64, n0 = ny * 64;
  int t = threadIdx.x, l = t & 63, w = t >> 6, wm = w >> 1, wn = w & 1;
  __shared__ __align__(16) char Asb[2][64 * 128];
  __shared__ __align__(16) char Bsb[2][64 * 128];
  int row = t >> 2, c0 = (t & 3) * 16;  // elems
  const __hip_bfloat16* pa = A + (size_t)(m0 + row) * lda + c0;
  const __hip_bfloat16* pb = B + (size_t)(n0 + row) * ldb + c0;
  bf16x8 ra0 = *(const bf16x8*)(pa);
  bf16x8 ra1 = *(const bf16x8*)(pa + 8);
  bf16x8 rb0 = *(const bf16x8*)(pb);
  bf16x8 rb1 = *(const bf16x8*)(pb + 8);
  int swzW = (row & 7) << 4;
  int waddr0 = row * 128 + ((c0 * 2) ^ swzW);
  int waddr1 = row * 128 + ((c0 * 2 + 16) ^ swzW);
  f32x4 acc[2][2] = {};
  int rA = wm * 32 + (l & 15), rB = wn * 32 + (l & 15);
  int swzR = (l & 7) << 4;           // (rA&7)<<4 == (rB&7)<<4 == ((l&15)&7)<<4
  int kbby = (l >> 4) * 16;          // bytes
  int p = 0;
  for (int k0 = 0; k0 < K; k0 += 64) {
    *(bf16x8*)(Asb[p] + waddr0) = ra0;
    *(bf16x8*)(Asb[p] + waddr1) = ra1;
    *(bf16x8*)(Bsb[p] + waddr0) = rb0;
    *(bf16x8*)(Bsb[p] + waddr1) = rb1;
    __syncthreads();
    if (k0 + 64 < K) {  // prefetch next K-tile into regs; hides under MFMA
      ra0 = *(const bf16x8*)(pa + k0 + 64);
      ra1 = *(const bf16x8*)(pa + k0 + 72);
      rb0 = *(const bf16x8*)(pb + k0 + 64);
      rb1 = *(const bf16x8*)(pb + k0 + 72);
    }
#pragma unroll
    for (int ks = 0; ks < 2; ++ks) {
      int cb = ks * 64 + kbby;
      bf16x8 a0 = *(const bf16x8*)(Asb[p] + rA * 128 + (cb ^ swzR));
      bf16x8 a1 = *(const bf16x8*)(Asb[p] + (rA + 16) * 128 + (cb ^ swzR));
      bf16x8 b0 = *(const bf16x8*)(Bsb[p] + rB * 128 + (cb ^ swzR));
      bf16x8 b1 = *(const bf16x8*)(Bsb[p] + (rB + 16) * 128 + (cb ^ swzR));
      acc[0][0] = __builtin_amdgcn_mfma_f32_16x16x32_bf16(a0, b0, acc[0][0], 0, 0, 0);
      acc[0][1] = __builtin_amdgcn_mfma_f32_16x16x32_bf16(a0, b1, acc[0][1], 0, 0, 0);
      acc[1][0] = __builtin_amdgcn_mfma_f32_16x16x32_bf16(a1, b0, acc[1][0], 0, 0, 0);
      acc[1][1] = __builtin_amdgcn_mfma_f32_16x16x32_bf16(a1, b1, acc[1][1], 0, 0, 0);
    }
    __syncthreads();
    p ^= 1;
  }
  int row0 = m0 + wm * 32 + ((l >> 4) << 2);
  int col0 = n0 + wn * 32 + (l & 15);
#pragma unroll
  for (int m = 0; m < 2; ++m)
#pragma unroll
    for (int n = 0; n < 2; ++n) {
      if (MODE == 0) {
#pragma unroll
        for (int r = 0; r < 4; ++r)
          C[(size_t)(row0 + m * 16 + r) * N + col0 + n * 16] = acc[m][n][r];
      } else {
        int colg = col0 + n * 16;
        int o = colg >> 8, j = colg & 255;
        float bo = bias[o];
        __hip_bfloat16* ob = outbf + (size_t)zz * sC;
#pragma unroll
        for (int r = 0; r < 4; ++r) {
          int i = row0 + m * 16 + r;
          ob[(((size_t)i + 1) * 258 + (j + 1)) * 16 + o] =
              __float2bfloat16(fmaxf(acc[m][n][r] + bo, 0.f));
        }
      }
    }
}

// ---------------- per-row select of the 5-way MLP + bias + mask --------------
__global__ __launch_bounds__(256) void select_kernel(const float* __restrict__ G5,
                                                     const float* __restrict__ b_nuc,
                                                     const float* __restrict__ wmask,
                                                     const int* __restrict__ nuc_ids,
                                                     __hip_bfloat16* __restrict__ pad_h) {
  int row = blockIdx.x;  // 0..511
  int b = row >> 8, l = row & 255;
  int t = threadIdx.x;
  int n = nuc_ids[row];
  n = n < 0 ? 0 : (n > 4 ? 4 : n);
  float wm = wmask[row];
  const float* g = G5 + (size_t)row * 3840 + (size_t)n * CH;
  const float* bn = b_nuc + (size_t)n * CH;
  __hip_bfloat16* dst = pad_h + ((size_t)b * 258 + l + 1) * CH;
#pragma unroll
  for (int q = 0; q < 3; ++q) {
    int d = q * 256 + t;
    dst[d] = __float2bfloat16((g[d] + bn[d]) * wm);
  }
}

// ------- cB[b][(o*256+j)][di*768+k] = sum_dj w_in[o,k,di,dj]*h[j+dj-1,k] -----
// vectorized: each thread does 12 (j,kg) pairs of 8 consecutive k.
__global__ __launch_bounds__(256) void c_kernel(const __hip_bfloat16* __restrict__ ph,
                                                const float* __restrict__ w_in,
                                                __hip_bfloat16* __restrict__ cB) {
  int jt = blockIdx.x;  // 0..7
  int od = blockIdx.y;  // 0..47  (o*3+di)
  int b = blockIdx.z;
  ph += (size_t)b * 258 * CH;
  cB += (size_t)b * 4096 * 2304;
  int o = od / 3, di = od % 3;
  int t = threadIdx.x;
  __shared__ float wk[3][CH];
  for (int idx = t; idx < 3 * CH; idx += 256) {
    int k = idx / 3, dj = idx % 3;
    wk[dj][k] = w_in[((size_t)(o * CH + k) * 3 + di) * 3 + dj];
  }
  __syncthreads();
  int j0 = jt * 32;
#pragma unroll
  for (int pp = 0; pp < 12; ++pp) {
    int pr = pp * 256 + t;          // 0..3071 = 32 j * 96 kg
    int jj = pr / 96, kg = pr % 96;
    int kbase = kg * 8;
    const __hip_bfloat16* hrow = ph + (size_t)(j0 + jj) * CH + kbase;  // pad rows j..j+2
    bf16x8 h0 = *(const bf16x8*)(hrow);
    bf16x8 h1 = *(const bf16x8*)(hrow + CH);
    bf16x8 h2 = *(const bf16x8*)(hrow + 2 * CH);
    bf16x8 r;
#pragma unroll
    for (int e = 0; e < 8; ++e) {
      int k = kbase + e;
      float acc = wk[0][k] * b2f(h0[e]) + wk[1][k] * b2f(h1[e]) + wk[2][k] * b2f(h2[e]);
      r[e] = f2b(acc);
    }
    *(bf16x8*)(cB + ((size_t)(o * 256 + j0 + jj) * 3 + di) * CH + kbase) = r;
  }
}

// ------- 16->16 3x3 conv, channels-last padded bf16, MFMA implicit GEMM ------
// act layout: [b][258][258][16] bf16, pad ring zero. out = relu(conv+bias[+res])
__global__ __launch_bounds__(256) void conv_mfma_kernel(const __hip_bfloat16* __restrict__ in,
                                                        const __hip_bfloat16* __restrict__ wq,
                                                        const float* __restrict__ bias,
                                                        const __hip_bfloat16* __restrict__ res,
                                                        __hip_bfloat16* __restrict__ outp) {
  __shared__ __hip_bfloat16 wl[16 * 160];
  int t = threadIdx.x;
  for (int idx = t; idx < 320; idx += 256)
    ((bf16x8*)wl)[idx] = ((const bf16x8*)wq)[idx];
  __syncthreads();
  int l = t & 63, w = t >> 6;
  int part = l >> 4, lane16 = l & 15;
  int hi = part >> 1, ch0 = (part & 1) * 8;
  int offs[5];
  bf16x8 wf[5];
#pragma unroll
  for (int kk = 0; kk < 5; ++kk) {
    int dd = 2 * kk + hi;
    if (dd > 8) dd = 0;  // k>=144 has zero weights; read a valid addr
    offs[kk] = ((dd / 3) * 258 + (dd % 3)) * 16;
    wf[kk] = *(const bf16x8*)&wl[lane16 * 160 + kk * 32 + part * 8];
  }
  float bo = bias[lane16];
#pragma unroll
  for (int it = 0; it < 2; ++it) {
    int g = (blockIdx.x * 4 + w) * 2 + it;  // 0..8191 pixel-groups
    int b = g >> 12, idx = g & 4095;
    int i = idx >> 4, j0 = (idx & 15) << 4;
    size_t base = (((size_t)b * 258 + i) * 258 + (j0 + lane16)) * 16 + ch0;
    f32x4 acc = {};
#pragma unroll
    for (int kk = 0; kk < 5; ++kk) {
      bf16x8 af = *(const bf16x8*)&in[base + offs[kk]];
      acc = __builtin_amdgcn_mfma_f32_16x16x32_bf16(af, wf[kk], acc, 0, 0, 0);
    }
    // D: col=lane16=o, row=part*4+r = pixel within group
    size_t obase = (((size_t)b * 258 + i + 1) * 258 + (j0 + part * 4 + 1)) * 16 + lane16;
#pragma unroll
    for (int r = 0; r < 4; ++r) {
      float v = acc[r] + bo;
      if (res) v += __bfloat162float(res[obase + (size_t)r * 16]);
      outp[obase + (size_t)r * 16] = __float2bfloat16(fmaxf(v, 0.f));
    }
  }
}

// ---------------- 1x1 head from channels-last bf16, fp32 output --------------
__global__ __launch_bounds__(256) void head_kernel(const __hip_bfloat16* __restrict__ y,
                                                   const float* __restrict__ w_out,
                                                   const float* __restrict__ b_out,
                                                   float* __restrict__ out) {
  __shared__ float wsm[16];
  int t = threadIdx.x;
  if (t < 16) wsm[t] = w_out[t];
  __syncthreads();
  int bi = blockIdx.x;  // b*256 + i
  int b = bi >> 8, i = bi & 255;
  const __hip_bfloat16* p = y + (((size_t)b * 258 + i + 1) * 258 + (t + 1)) * 16;
  float s = b_out[0];
#pragma unroll
  for (int o = 0; o < 16; ++o) s += wsm[o] * __bfloat162float(p[o]);
  out[(size_t)bi * 256 + t] = s;
}

extern "C" void kernel_launch(void* const* d_in, const int* in_sizes, int n_in,
                              void* d_out, int out_size, void* d_ws, size_t ws_size,
                              hipStream_t stream) {
  const float* hidden = (const float*)d_in[0];
  const float* wmask = (const float*)d_in[1];
  const float* W_nuc = (const float*)d_in[2];
  const float* b_nuc = (const float*)d_in[3];
  const float* w_in = (const float*)d_in[4];
  const float* b_in = (const float*)d_in[5];
  const float* w1a = (const float*)d_in[6];
  const float* b1a = (const float*)d_in[7];
  const float* w1b = (const float*)d_in[8];
  const float* b1b = (const float*)d_in[9];
  const float* w2a = (const float*)d_in[10];
  const float* b2a = (const float*)d_in[11];
  const float* w2b = (const float*)d_in[12];
  const float* b2b = (const float*)d_in[13];
  const float* w_out = (const float*)d_in[14];
  const float* b_out = (const float*)d_in[15];
  const int* ptl = (const int*)d_in[16];
  const int* nuc_ids = (const int*)d_in[17];
  float* out = (float*)d_out;

  // workspace layout (no aliasing; ~65.1 MB of ~256 MiB)
  char* ws = (char*)d_ws;
  __hip_bfloat16* pad_h = (__hip_bfloat16*)(ws);                // 792,576
  __hip_bfloat16* Wp = (__hip_bfloat16*)(ws + 792576);          // 5,898,240 (ends 6,690,816)
  float* G5 = (float*)(ws + 6690816);                           // 7,864,320 (ends 14,555,136)
  __hip_bfloat16* cB = (__hip_bfloat16*)(ws + 14555136);        // 2*18,874,368 (ends 52,303,872)
  __hip_bfloat16* act0 = (__hip_bfloat16*)(ws + 52303872);      // 4,259,328 (ends 56,563,200)
  __hip_bfloat16* act1 = (__hip_bfloat16*)(ws + 56563200);      // 4,259,328 (ends 60,822,528)
  __hip_bfloat16* act2 = (__hip_bfloat16*)(ws + 60822528);      // 4,259,328 (ends 65,081,856)
  __hip_bfloat16* wq = (__hip_bfloat16*)(ws + 65081856);        // 20,480 (ends 65,102,336)

  const long PHB = 258 * CH;          // per-batch pad_h stride (elements)
  const long ACT = 258 * 258 * 16;    // per-batch act stride (elements)
  const long CBS = (long)4096 * 2304; // per-batch cB stride (elements)

  pack_w_kernel<<<720, 256, 0, stream>>>(W_nuc, Wp);
  pack_wq_kernel<<<4, 256, 0, stream>>>(w1a, w1b, w2a, w2b, wq);
  hipMemsetAsync(act0, 0, 12777984, stream);  // zero all three act pad rings
  tok_gather_kernel<<<512, 256, 0, stream>>>(hidden, ptl, pad_h);
  // phase-A: G5[b*256+l][n*768+d] = map @ Wp^T   (M=256/batch, N=3840, K=768)
  gemm64_kernel<0><<<dim3(4, 60, 2), 256, 0, stream>>>(
      pad_h + CH, Wp, G5, 3840, CH, CH, CH, PHB, 0, (long)256 * 3840, nullptr, nullptr);
  select_kernel<<<512, 256, 0, stream>>>(G5, b_nuc, wmask, nuc_ids, pad_h);
  // stem, both batches: c-precompute (z=2), then fused GEMM (XCD-swizzled 1-D grid)
  c_kernel<<<dim3(8, 48, 2), 256, 0, stream>>>(pad_h, w_in, cB);
  gemm64_kernel<1><<<512, 256, 0, stream>>>(
      pad_h, cB, nullptr, 4096, 2304, CH, 2304, PHB, CBS, ACT, b_in, act0);
  conv_mfma_kernel<<<1024, 256, 0, stream>>>(act0, wq, b1a, nullptr, act1);
  conv_mfma_kernel<<<1024, 256, 0, stream>>>(act1, wq + 2560, b1b, act0, act2);
  conv_mfma_kernel<<<1024, 256, 0, stream>>>(act2, wq + 5120, b2a, nullptr, act1);
  conv_mfma_kernel<<<1024, 256, 0, stream>>>(act1, wq + 7680, b2b, act2, act0);
  head_kernel<<<512, 256, 0, stream>>>(act0, w_out, b_out, out);
}

// Round 13
// 188.398 us; speedup vs baseline: 2.4715x; 1.0320x over previous
//
#include <hip/hip_runtime.h>
#include <hip/hip_bf16.h>

#define LL 256
#define TT 128
#define CH 768
#define NB 16

typedef __attribute__((ext_vector_type(8))) short bf16x8;
typedef __attribute__((ext_vector_type(4))) float f32x4;

__device__ __forceinline__ float b2f(short s) {
  union { unsigned u; float f; } x;
  x.u = ((unsigned)(unsigned short)s) << 16;
  return x.f;
}
__device__ __forceinline__ short f2b(float v) {
  __hip_bfloat16 hb = __float2bfloat16(v);
  return *reinterpret_cast<short*>(&hb);
}

// ---------------- pack W_nuc transposed to bf16: Wp[(n*768+d)][c] = W[n][c][d] ----
__global__ __launch_bounds__(256) void pack_w_kernel(const float* __restrict__ W,
                                                     __hip_bfloat16* __restrict__ Wp) {
  __shared__ float s[64][65];
  int bid = blockIdx.x;
  int n = bid / 144, rem = bid % 144;
  int c0 = (rem / 12) * 64, d0 = (rem % 12) * 64;
  int t = threadIdx.x;
  int col = t & 63, rr = t >> 6;
  const float* Wn = W + (size_t)n * CH * CH;
#pragma unroll
  for (int it = 0; it < 16; ++it) {
    int r = it * 4 + rr;
    s[r][col] = Wn[(size_t)(c0 + r) * CH + d0 + col];
  }
  __syncthreads();
#pragma unroll
  for (int it = 0; it < 16; ++it) {
    int r = it * 4 + rr;  // d-offset
    Wp[(size_t)(n * CH + d0 + r) * CH + c0 + col] = __float2bfloat16(s[col][r]);
  }
}

// ---------------- pack conv weights: wq[c][o][kq], kq = dd*16+ch, 160 padded ----
__global__ __launch_bounds__(256) void pack_wq_kernel(const float* __restrict__ wa,
                                                      const float* __restrict__ wb,
                                                      const float* __restrict__ wc,
                                                      const float* __restrict__ wd,
                                                      __hip_bfloat16* __restrict__ wq) {
  const float* srcs[4] = {wa, wb, wc, wd};
  int c = blockIdx.x;
  const float* src = srcs[c];
  int t = threadIdx.x;
  for (int idx = t; idx < 2560; idx += 256) {
    int o = idx / 160, kq = idx % 160;
    int dd = kq >> 4, ch = kq & 15;
    float v = (dd < 9) ? src[(o * 16 + ch) * 9 + dd] : 0.f;  // w[o][ch][di][dj]
    wq[c * 2560 + idx] = __float2bfloat16(v);
  }
}

// ---------------- token->nucleotide map (bf16), unpadded [b*256+l][768] ------
__global__ __launch_bounds__(256) void tok_gather_kernel(const float* __restrict__ hidden,
                                                         const int* __restrict__ ptl,
                                                         __hip_bfloat16* __restrict__ map) {
  int bid = blockIdx.x;  // b*256 + l
  int b = bid >> 8, l = bid & 255;
  __shared__ int vals[TT];
  __shared__ int tok_s;
  int t = threadIdx.x;
  if (t < TT) vals[t] = ptl[b * TT + t];
  __syncthreads();
  if (t == 0) {
    int run = 0, tk = 0;
    for (int q = 0; q < TT; ++q) { run += vals[q]; tk += (run <= l) ? 1 : 0; }
    tok_s = tk < TT ? tk : TT - 1;
  }
  __syncthreads();
  const float* src = hidden + ((size_t)b * TT + tok_s) * CH;
  __hip_bfloat16* dst = map + (size_t)bid * CH;
#pragma unroll
  for (int q = 0; q < 3; ++q) dst[q * 256 + t] = __float2bfloat16(src[q * 256 + t]);
}

// ------- 64x64-tile bf16 MFMA GEMM, K-step 64, reg-dbuf LDS, XOR-swizzled ----
// C = A * B^T (B stored [N][K]).
// MODE 0: fp32 store to C (ld = N), 3-D grid (mx, ny, z).
// MODE 1: 1-D grid of 512, XCD-swizzled. Stem epilogue: col=(o<<8)|j ->
//         outbf[z*sC + ((row+1)*258+(j+1))*16+o] = bf16(relu(acc+bias[o])).
// MODE 2: 3-D grid. Fused nucleotide-select epilogue: nid=colg/768, d=colg%768;
//         if (nuc_ids[z*256+row]==nid) outbf[z*sC+(row+1)*768+d] =
//         bf16((acc+bias[colg])*wmask[z*256+row]).  (outbf pre-zeroed.)
template <int MODE>
__global__ __launch_bounds__(256) void gemm64_kernel(const __hip_bfloat16* __restrict__ A,
                                                     const __hip_bfloat16* __restrict__ B,
                                                     float* __restrict__ C,
                                                     int N, int K, int lda, int ldb,
                                                     long sA, long sB, long sC,
                                                     const float* __restrict__ bias,
                                                     __hip_bfloat16* __restrict__ outbf,
                                                     const int* __restrict__ nuc_ids,
                                                     const float* __restrict__ wmask) {
  int mx, ny, zz;
  if (MODE == 1) {
    int bid = blockIdx.x;
    mx = (bid >> 3) & 3;
    int pair = (bid >> 5) * 8 + (bid & 7);
    ny = pair >> 1;
    zz = pair & 1;
  } else {
    mx = blockIdx.x; ny = blockIdx.y; zz = blockIdx.z;
  }
  A += (size_t)zz * sA;
  B += (size_t)zz * sB;
  if (MODE == 0) C += (size_t)zz * sC;
  int m0 = mx * 64, n0 = ny * 64;
  int t = threadIdx.x, l = t & 63, w = t >> 6, wm = w >> 1, wn = w & 1;
  __shared__ __align__(16) char Asb[2][64 * 128];
  __shared__ __align__(16) char Bsb[2][64 * 128];
  int row = t >> 2, c0 = (t & 3) * 16;  // elems
  const __hip_bfloat16* pa = A + (size_t)(m0 + row) * lda + c0;
  const __hip_bfloat16* pb = B + (size_t)(n0 + row) * ldb + c0;
  bf16x8 ra0 = *(const bf16x8*)(pa);
  bf16x8 ra1 = *(const bf16x8*)(pa + 8);
  bf16x8 rb0 = *(const bf16x8*)(pb);
  bf16x8 rb1 = *(const bf16x8*)(pb + 8);
  int swzW = (row & 7) << 4;
  int waddr0 = row * 128 + ((c0 * 2) ^ swzW);
  int waddr1 = row * 128 + ((c0 * 2 + 16) ^ swzW);
  f32x4 acc[2][2] = {};
  int rA = wm * 32 + (l & 15), rB = wn * 32 + (l & 15);
  int swzR = (l & 7) << 4;           // (rA&7)<<4 == (rB&7)<<4 == ((l&15)&7)<<4
  int kbby = (l >> 4) * 16;          // bytes
  int p = 0;
  for (int k0 = 0; k0 < K; k0 += 64) {
    *(bf16x8*)(Asb[p] + waddr0) = ra0;
    *(bf16x8*)(Asb[p] + waddr1) = ra1;
    *(bf16x8*)(Bsb[p] + waddr0) = rb0;
    *(bf16x8*)(Bsb[p] + waddr1) = rb1;
    __syncthreads();
    if (k0 + 64 < K) {  // prefetch next K-tile into regs; hides under MFMA
      ra0 = *(const bf16x8*)(pa + k0 + 64);
      ra1 = *(const bf16x8*)(pa + k0 + 72);
      rb0 = *(const bf16x8*)(pb + k0 + 64);
      rb1 = *(const bf16x8*)(pb + k0 + 72);
    }
#pragma unroll
    for (int ks = 0; ks < 2; ++ks) {
      int cb = ks * 64 + kbby;
      bf16x8 a0 = *(const bf16x8*)(Asb[p] + rA * 128 + (cb ^ swzR));
      bf16x8 a1 = *(const bf16x8*)(Asb[p] + (rA + 16) * 128 + (cb ^ swzR));
      bf16x8 b0 = *(const bf16x8*)(Bsb[p] + rB * 128 + (cb ^ swzR));
      bf16x8 b1 = *(const bf16x8*)(Bsb[p] + (rB + 16) * 128 + (cb ^ swzR));
      acc[0][0] = __builtin_amdgcn_mfma_f32_16x16x32_bf16(a0, b0, acc[0][0], 0, 0, 0);
      acc[0][1] = __builtin_amdgcn_mfma_f32_16x16x32_bf16(a0, b1, acc[0][1], 0, 0, 0);
      acc[1][0] = __builtin_amdgcn_mfma_f32_16x16x32_bf16(a1, b0, acc[1][0], 0, 0, 0);
      acc[1][1] = __builtin_amdgcn_mfma_f32_16x16x32_bf16(a1, b1, acc[1][1], 0, 0, 0);
    }
    __syncthreads();
    p ^= 1;
  }
  int row0 = m0 + wm * 32 + ((l >> 4) << 2);
  int col0 = n0 + wn * 32 + (l & 15);
#pragma unroll
  for (int m = 0; m < 2; ++m)
#pragma unroll
    for (int n = 0; n < 2; ++n) {
      if (MODE == 0) {
#pragma unroll
        for (int r = 0; r < 4; ++r)
          C[(size_t)(row0 + m * 16 + r) * N + col0 + n * 16] = acc[m][n][r];
      } else if (MODE == 1) {
        int colg = col0 + n * 16;
        int o = colg >> 8, j = colg & 255;
        float bo = bias[o];
        __hip_bfloat16* ob = outbf + (size_t)zz * sC;
#pragma unroll
        for (int r = 0; r < 4; ++r) {
          int i = row0 + m * 16 + r;
          ob[(((size_t)i + 1) * 258 + (j + 1)) * 16 + o] =
              __float2bfloat16(fmaxf(acc[m][n][r] + bo, 0.f));
        }
      } else {  // MODE 2: fused 5-way select -> pad_h2 (pre-zeroed)
        int colg = col0 + n * 16;
        int nid = colg / 768, d = colg % 768;
        float bn = bias[colg];  // b_nuc flat [5*768]
        __hip_bfloat16* ob = outbf + (size_t)zz * sC;
#pragma unroll
        for (int r = 0; r < 4; ++r) {
          int rowg = row0 + m * 16 + r;
          if (nuc_ids[zz * 256 + rowg] == nid) {
            float wmv = wmask[zz * 256 + rowg];
            ob[(size_t)(rowg + 1) * CH + d] =
                __float2bfloat16((acc[m][n][r] + bn) * wmv);
          }
        }
      }
    }
}

// ------- cB[b][(o*256+j)][di*768+k] = sum_dj w_in[o,k,di,dj]*h[j+dj-1,k] -----
// vectorized: each thread does 12 (j,kg) pairs of 8 consecutive k.
__global__ __launch_bounds__(256) void c_kernel(const __hip_bfloat16* __restrict__ ph,
                                                const float* __restrict__ w_in,
                                                __hip_bfloat16* __restrict__ cB) {
  int jt = blockIdx.x;  // 0..7
  int od = blockIdx.y;  // 0..47  (o*3+di)
  int b = blockIdx.z;
  ph += (size_t)b * 258 * CH;
  cB += (size_t)b * 4096 * 2304;
  int o = od / 3, di = od % 3;
  int t = threadIdx.x;
  __shared__ float wk[3][CH];
  for (int idx = t; idx < 3 * CH; idx += 256) {
    int k = idx / 3, dj = idx % 3;
    wk[dj][k] = w_in[((size_t)(o * CH + k) * 3 + di) * 3 + dj];
  }
  __syncthreads();
  int j0 = jt * 32;
#pragma unroll
  for (int pp = 0; pp < 12; ++pp) {
    int pr = pp * 256 + t;          // 0..3071 = 32 j * 96 kg
    int jj = pr / 96, kg = pr % 96;
    int kbase = kg * 8;
    const __hip_bfloat16* hrow = ph + (size_t)(j0 + jj) * CH + kbase;  // pad rows j..j+2
    bf16x8 h0 = *(const bf16x8*)(hrow);
    bf16x8 h1 = *(const bf16x8*)(hrow + CH);
    bf16x8 h2 = *(const bf16x8*)(hrow + 2 * CH);
    bf16x8 r;
#pragma unroll
    for (int e = 0; e < 8; ++e) {
      int k = kbase + e;
      float acc = wk[0][k] * b2f(h0[e]) + wk[1][k] * b2f(h1[e]) + wk[2][k] * b2f(h2[e]);
      r[e] = f2b(acc);
    }
    *(bf16x8*)(cB + ((size_t)(o * 256 + j0 + jj) * 3 + di) * CH + kbase) = r;
  }
}

// ------- 16->16 3x3 conv, channels-last padded bf16, MFMA implicit GEMM ------
// act layout: [b][258][258][16] bf16, pad ring zero. out = relu(conv+bias[+res])
// HEAD=1: instead of storing, apply 1x1 head (w_out,b_out) via 16-lane
// shfl-xor reduce over o and write fp32 out[b][i][j].
template <int HEAD>
__global__ __launch_bounds__(256) void conv_mfma_kernel(const __hip_bfloat16* __restrict__ in,
                                                        const __hip_bfloat16* __restrict__ wq,
                                                        const float* __restrict__ bias,
                                                        const __hip_bfloat16* __restrict__ res,
                                                        __hip_bfloat16* __restrict__ outp,
                                                        const float* __restrict__ w_out,
                                                        const float* __restrict__ b_out,
                                                        float* __restrict__ outf) {
  __shared__ __hip_bfloat16 wl[16 * 160];
  int t = threadIdx.x;
  for (int idx = t; idx < 320; idx += 256)
    ((bf16x8*)wl)[idx] = ((const bf16x8*)wq)[idx];
  __syncthreads();
  int l = t & 63, w = t >> 6;
  int part = l >> 4, lane16 = l & 15;
  int hi = part >> 1, ch0 = (part & 1) * 8;
  int offs[5];
  bf16x8 wf[5];
#pragma unroll
  for (int kk = 0; kk < 5; ++kk) {
    int dd = 2 * kk + hi;
    if (dd > 8) dd = 0;  // k>=144 has zero weights; read a valid addr
    offs[kk] = ((dd / 3) * 258 + (dd % 3)) * 16;
    wf[kk] = *(const bf16x8*)&wl[lane16 * 160 + kk * 32 + part * 8];
  }
  float bo = bias[lane16];
  float wout = HEAD ? w_out[lane16] : 0.f;
  float bout = HEAD ? b_out[0] : 0.f;
#pragma unroll
  for (int it = 0; it < 2; ++it) {
    int g = (blockIdx.x * 4 + w) * 2 + it;  // 0..8191 pixel-groups
    int b = g >> 12, idx = g & 4095;
    int i = idx >> 4, j0 = (idx & 15) << 4;
    size_t base = (((size_t)b * 258 + i) * 258 + (j0 + lane16)) * 16 + ch0;
    f32x4 acc = {};
#pragma unroll
    for (int kk = 0; kk < 5; ++kk) {
      bf16x8 af = *(const bf16x8*)&in[base + offs[kk]];
      acc = __builtin_amdgcn_mfma_f32_16x16x32_bf16(af, wf[kk], acc, 0, 0, 0);
    }
    // D: col=lane16=o, row=part*4+r = pixel within group
    size_t obase = (((size_t)b * 258 + i + 1) * 258 + (j0 + part * 4 + 1)) * 16 + lane16;
#pragma unroll
    for (int r = 0; r < 4; ++r) {
      float v = acc[r] + bo;
      if (res) v += __bfloat162float(res[obase + (size_t)r * 16]);
      v = fmaxf(v, 0.f);
      if (HEAD) {
        float hv = v * wout;
        hv += __shfl_xor(hv, 1);
        hv += __shfl_xor(hv, 2);
        hv += __shfl_xor(hv, 4);
        hv += __shfl_xor(hv, 8);
        if (lane16 == 0)
          outf[((size_t)b * 256 + i) * 256 + j0 + part * 4 + r] = hv + bout;
      } else {
        outp[obase + (size_t)r * 16] = __float2bfloat16(v);
      }
    }
  }
}

extern "C" void kernel_launch(void* const* d_in, const int* in_sizes, int n_in,
                              void* d_out, int out_size, void* d_ws, size_t ws_size,
                              hipStream_t stream) {
  const float* hidden = (const float*)d_in[0];
  const float* wmask = (const float*)d_in[1];
  const float* W_nuc = (const float*)d_in[2];
  const float* b_nuc = (const float*)d_in[3];
  const float* w_in = (const float*)d_in[4];
  const float* b_in = (const float*)d_in[5];
  const float* w1a = (const float*)d_in[6];
  const float* b1a = (const float*)d_in[7];
  const float* w1b = (const float*)d_in[8];
  const float* b1b = (const float*)d_in[9];
  const float* w2a = (const float*)d_in[10];
  const float* b2a = (const float*)d_in[11];
  const float* w2b = (const float*)d_in[12];
  const float* b2b = (const float*)d_in[13];
  const float* w_out = (const float*)d_in[14];
  const float* b_out = (const float*)d_in[15];
  const int* ptl = (const int*)d_in[16];
  const int* nuc_ids = (const int*)d_in[17];
  float* out = (float*)d_out;

  // workspace layout (~58 MB of ~256 MiB)
  char* ws = (char*)d_ws;
  __hip_bfloat16* map = (__hip_bfloat16*)(ws);                  // 786,432
  __hip_bfloat16* Wp = (__hip_bfloat16*)(ws + 786432);          // 5,898,240 (ends 6,684,672)
  __hip_bfloat16* cB = (__hip_bfloat16*)(ws + 6684672);         // 37,748,736 (ends 44,433,408)
  __hip_bfloat16* pad_h2 = (__hip_bfloat16*)(ws + 44433408);    // 792,576 (ends 45,225,984)
  __hip_bfloat16* act0 = (__hip_bfloat16*)(ws + 45225984);      // 4,259,328 (ends 49,485,312)
  __hip_bfloat16* act1 = (__hip_bfloat16*)(ws + 49485312);      // 4,259,328 (ends 53,744,640)
  __hip_bfloat16* act2 = (__hip_bfloat16*)(ws + 53744640);      // 4,259,328 (ends 58,003,968)
  __hip_bfloat16* wq = (__hip_bfloat16*)(ws + 58003968);        // 20,480 (ends 58,024,448)

  const long PHB = 258 * CH;          // per-batch pad_h2 stride (elements)
  const long ACT = 258 * 258 * 16;    // per-batch act stride (elements)
  const long CBS = (long)4096 * 2304; // per-batch cB stride (elements)

  pack_w_kernel<<<720, 256, 0, stream>>>(W_nuc, Wp);
  pack_wq_kernel<<<4, 256, 0, stream>>>(w1a, w1b, w2a, w2b, wq);
  // zero pad_h2 (select target; zero == one_hot-of-OOB semantics) + act rings
  hipMemsetAsync(pad_h2, 0, 792576 + 12777984, stream);
  tok_gather_kernel<<<512, 256, 0, stream>>>(hidden, ptl, map);
  // phase-A GEMM + fused select: h -> pad_h2 (M=256/batch, N=3840, K=768)
  gemm64_kernel<2><<<dim3(4, 60, 2), 256, 0, stream>>>(
      map, Wp, nullptr, 3840, CH, CH, CH, (long)256 * CH, 0, PHB,
      b_nuc, pad_h2, nuc_ids, wmask);
  // stem: c-precompute (z=2), then fused GEMM (XCD-swizzled 1-D grid)
  c_kernel<<<dim3(8, 48, 2), 256, 0, stream>>>(pad_h2, w_in, cB);
  gemm64_kernel<1><<<512, 256, 0, stream>>>(
      pad_h2, cB, nullptr, 4096, 2304, CH, 2304, PHB, CBS, ACT,
      b_in, act0, nullptr, nullptr);
  conv_mfma_kernel<0><<<1024, 256, 0, stream>>>(act0, wq, b1a, nullptr, act1,
                                                nullptr, nullptr, nullptr);
  conv_mfma_kernel<0><<<1024, 256, 0, stream>>>(act1, wq + 2560, b1b, act0, act2,
                                                nullptr, nullptr, nullptr);
  conv_mfma_kernel<0><<<1024, 256, 0, stream>>>(act2, wq + 5120, b2a, nullptr, act1,
                                                nullptr, nullptr, nullptr);
  // conv4 + fused 1x1 head -> fp32 out
  conv_mfma_kernel<1><<<1024, 256, 0, stream>>>(act1, wq + 7680, b2b, act2, nullptr,
                                                w_out, b_out, out);
}